// Round 1
// baseline (539.440 us; speedup 1.0000x reference)
//
#include <hip/hip_runtime.h>

typedef unsigned short ushort_t;
typedef __attribute__((ext_vector_type(8))) short bf16x8;   // 8 bf16 in 4 VGPRs
typedef __attribute__((ext_vector_type(4))) float f32x4;

#define H 512
#define E 1024
#define S 2048
#define B 32

__device__ __forceinline__ ushort_t f2bf(float f) {
    unsigned u = __float_as_uint(f);
    unsigned r = (u + 0x7FFFu + ((u >> 16) & 1u)) >> 16;   // round-to-nearest-even
    return (ushort_t)r;
}

// hb[b][h] = hidden[b] @ Wh + ba   (Wh = Wa[:512])
__global__ void prep_hb(const float* __restrict__ hidden, const float* __restrict__ Wa,
                        const float* __restrict__ ba, float* __restrict__ hb) {
    int b = blockIdx.x, tid = threadIdx.x;
    __shared__ float hs[H];
    hs[tid]       = hidden[b * H + tid];
    hs[tid + 256] = hidden[b * H + tid + 256];
    __syncthreads();
    float a0 = 0.f, a1 = 0.f;
    for (int k = 0; k < H; ++k) {
        float hv = hs[k];
        a0 += hv * Wa[(size_t)k * H + tid];
        a1 += hv * Wa[(size_t)k * H + tid + 256];
    }
    hb[b * H + tid]       = a0 + ba[tid];
    hb[b * H + tid + 256] = a1 + ba[tid + 256];
}

// Swizzle We (= Wa[512:]) into bf16 MFMA-B-fragment order:
// wef[((kt*32+nt)*64 + lane)*8 + j] = We[kt*32 + (lane>>4)*8 + j][nt*16 + (lane&15)]
__global__ void prep_wef(const float* __restrict__ Wa, ushort_t* __restrict__ wef) {
    int g = blockIdx.x * 256 + threadIdx.x;      // 0..65535
    int kt = g >> 11, nt = (g >> 6) & 31, l = g & 63;
    int kbase = kt * 32 + ((l >> 4) << 3);
    int n = nt * 16 + (l & 15);
    #pragma unroll
    for (int j = 0; j < 8; ++j)
        wef[(size_t)g * 8 + j] = f2bf(Wa[(size_t)(H + kbase + j) * H + n]);
}

// Fused: scores[b][s] = v . tanh( enc[b,s,:] @ We + hb[b,:] )
// WG: 256 thr (4 waves), tile M=64 (s) x N=512 (all h), K=1024 in chunks of 64.
// Wave w owns n in [w*128, w*128+128). A staged fp32->bf16 in LDS (pad 72), B from L2.
__launch_bounds__(256, 2)
__global__ void score_kernel(const float* __restrict__ enc, const ushort_t* __restrict__ wef,
                             const float* __restrict__ hb, const float* __restrict__ v,
                             float* __restrict__ scores) {
    int b = blockIdx.y;
    int s0 = blockIdx.x * 64;
    int tid = threadIdx.x;
    int wave = tid >> 6, lane = tid & 63;
    int q = lane >> 4, nl = lane & 15;

    __shared__ ushort_t As[64 * 72];      // 64 rows x 64 k, pad to 72 (144B stride, 16B-aligned)
    __shared__ float sred[4][64];

    f32x4 acc[4][8] = {};

    const float* Arow = enc + ((size_t)b * S + s0) * E;
    int srow = tid >> 3;            // 0..31
    int scol = (tid & 7) * 8;       // 0,8,..,56

    for (int kb = 0; kb < 16; ++kb) {
        #pragma unroll
        for (int it = 0; it < 2; ++it) {
            int r = srow + it * 32;
            const float* src = Arow + (size_t)r * E + kb * 64 + scol;
            float4 x = *(const float4*)src;
            float4 y = *(const float4*)(src + 4);
            uint4 u;
            u.x = (unsigned)f2bf(x.x) | ((unsigned)f2bf(x.y) << 16);
            u.y = (unsigned)f2bf(x.z) | ((unsigned)f2bf(x.w) << 16);
            u.z = (unsigned)f2bf(y.x) | ((unsigned)f2bf(y.y) << 16);
            u.w = (unsigned)f2bf(y.z) | ((unsigned)f2bf(y.w) << 16);
            *(uint4*)&As[r * 72 + scol] = u;
        }
        __syncthreads();
        #pragma unroll
        for (int ks = 0; ks < 2; ++ks) {
            int kt = kb * 2 + ks;
            bf16x8 afr[4];
            #pragma unroll
            for (int mt = 0; mt < 4; ++mt) {
                int m = mt * 16 + nl;
                afr[mt] = *(const bf16x8*)&As[m * 72 + ks * 32 + q * 8];
            }
            #pragma unroll
            for (int ntl = 0; ntl < 8; ++ntl) {
                int nt = wave * 8 + ntl;
                bf16x8 bfr = *(const bf16x8*)&wef[((size_t)(kt * 32 + nt) * 64 + lane) * 8];
                #pragma unroll
                for (int mt = 0; mt < 4; ++mt)
                    acc[mt][ntl] = __builtin_amdgcn_mfma_f32_16x16x32_bf16(
                        afr[mt], bfr, acc[mt][ntl], 0, 0, 0);
            }
        }
        __syncthreads();
    }

    // Epilogue: C elem (m = mt*16 + q*4 + r, n = wave*128 + ntl*16 + nl)
    float p[16];
    #pragma unroll
    for (int i = 0; i < 16; ++i) p[i] = 0.f;
    #pragma unroll
    for (int ntl = 0; ntl < 8; ++ntl) {
        int n = wave * 128 + ntl * 16 + nl;
        float hv = hb[b * H + n];
        float vv = v[n];
        #pragma unroll
        for (int mt = 0; mt < 4; ++mt)
            #pragma unroll
            for (int r = 0; r < 4; ++r)
                p[mt * 4 + r] += vv * tanhf(acc[mt][ntl][r] + hv);
    }
    #pragma unroll
    for (int off = 1; off < 16; off <<= 1) {
        #pragma unroll
        for (int i = 0; i < 16; ++i) p[i] += __shfl_xor(p[i], off, 64);
    }
    if (nl == 0) {
        #pragma unroll
        for (int mt = 0; mt < 4; ++mt)
            #pragma unroll
            for (int r = 0; r < 4; ++r)
                sred[wave][mt * 16 + q * 4 + r] = p[mt * 4 + r];
    }
    __syncthreads();
    if (tid < 64) {
        float s = sred[0][tid] + sred[1][tid] + sred[2][tid] + sred[3][tid];
        scores[(size_t)b * S + s0 + tid] = s;
    }
}

// softmax over S per b; writes attention weights to out[B*E + ...] and zeros context region
__global__ void softmax_kernel(const float* __restrict__ scores, float* __restrict__ out) {
    int b = blockIdx.x, tid = threadIdx.x;
    const float* row = scores + (size_t)b * S;
    float loc[8];
    float mx = -3.4e38f;
    #pragma unroll
    for (int i = 0; i < 8; ++i) { loc[i] = row[tid + i * 256]; mx = fmaxf(mx, loc[i]); }
    #pragma unroll
    for (int off = 32; off > 0; off >>= 1) mx = fmaxf(mx, __shfl_xor(mx, off, 64));
    __shared__ float wm[4], wsm[4];
    if ((tid & 63) == 0) wm[tid >> 6] = mx;
    __syncthreads();
    mx = fmaxf(fmaxf(wm[0], wm[1]), fmaxf(wm[2], wm[3]));
    float sum = 0.f;
    #pragma unroll
    for (int i = 0; i < 8; ++i) { loc[i] = __expf(loc[i] - mx); sum += loc[i]; }
    #pragma unroll
    for (int off = 32; off > 0; off >>= 1) sum += __shfl_xor(sum, off, 64);
    if ((tid & 63) == 0) wsm[tid >> 6] = sum;
    __syncthreads();
    sum = wsm[0] + wsm[1] + wsm[2] + wsm[3];
    float inv = 1.f / sum;
    #pragma unroll
    for (int i = 0; i < 8; ++i) out[B * E + (size_t)b * S + tid + i * 256] = loc[i] * inv;
    #pragma unroll
    for (int i = 0; i < 4; ++i) out[(size_t)b * E + tid + i * 256] = 0.f;   // zero context for atomics
}

// context[b][e] = sum_s w[b][s] * enc[b][s][e]; grid (etile, schunk, b)
__global__ void context_kernel(const float* __restrict__ enc, const float* __restrict__ w_attn,
                               float* __restrict__ out_ctx) {
    int et = blockIdx.x, sc = blockIdx.y, b = blockIdx.z;
    int e = et * 256 + threadIdx.x;
    const float* w  = w_attn + (size_t)b * S + sc * 256;
    const float* ep = enc + ((size_t)b * S + sc * 256) * E + e;
    float acc = 0.f;
    #pragma unroll 4
    for (int s = 0; s < 256; ++s) acc += w[s] * ep[(size_t)s * E];
    atomicAdd(&out_ctx[(size_t)b * E + e], acc);
}

extern "C" void kernel_launch(void* const* d_in, const int* in_sizes, int n_in,
                              void* d_out, int out_size, void* d_ws, size_t ws_size,
                              hipStream_t stream) {
    const float* hidden = (const float*)d_in[0];
    const float* enc    = (const float*)d_in[1];
    const float* Wa     = (const float*)d_in[2];
    const float* ba     = (const float*)d_in[3];
    const float* v      = (const float*)d_in[4];
    float* out = (float*)d_out;

    char* ws = (char*)d_ws;
    ushort_t* wef = (ushort_t*)ws;                        // 1 MiB  (bf16 We fragments)
    float* hb     = (float*)(ws + (1 << 20));             // 64 KiB
    float* scores = (float*)(ws + (1 << 20) + (1 << 16)); // 256 KiB

    prep_hb<<<B, 256, 0, stream>>>(hidden, Wa, ba, hb);
    prep_wef<<<256, 256, 0, stream>>>(Wa, wef);
    score_kernel<<<dim3(S / 64, B), 256, 0, stream>>>(enc, wef, hb, v, scores);
    softmax_kernel<<<B, 256, 0, stream>>>(scores, out);
    context_kernel<<<dim3(4, 8, B), 256, 0, stream>>>(enc, out + B * E, out);
}

// Round 2
// 516.249 us; speedup vs baseline: 1.0449x; 1.0449x over previous
//
#include <hip/hip_runtime.h>

typedef unsigned short ushort_t;
typedef __attribute__((ext_vector_type(8))) short bf16x8;   // 8 bf16 in 4 VGPRs
typedef __attribute__((ext_vector_type(4))) float f32x4;

#define H 512
#define E 1024
#define S 2048
#define B 32

__device__ __forceinline__ ushort_t f2bf(float f) {
    unsigned u = __float_as_uint(f);
    unsigned r = (u + 0x7FFFu + ((u >> 16) & 1u)) >> 16;   // round-to-nearest-even
    return (ushort_t)r;
}

// hb[b][h] = hidden[b] @ Wh + ba  — split-K over 8 chunks, atomicAdd into zeroed hb
__global__ void prep_hb(const float* __restrict__ hidden, const float* __restrict__ Wa,
                        const float* __restrict__ ba, float* __restrict__ hb) {
    int b = blockIdx.x, kc = blockIdx.y, tid = threadIdx.x;
    const float* hp = hidden + b * H + kc * 64;
    float a0 = 0.f, a1 = 0.f;
    #pragma unroll 8
    for (int k = 0; k < 64; ++k) {
        float hv = hp[k];
        a0 += hv * Wa[(size_t)(kc * 64 + k) * H + tid];
        a1 += hv * Wa[(size_t)(kc * 64 + k) * H + tid + 256];
    }
    if (kc == 0) { a0 += ba[tid]; a1 += ba[tid + 256]; }
    atomicAdd(&hb[b * H + tid], a0);
    atomicAdd(&hb[b * H + tid + 256], a1);
}

// Swizzle We (= Wa[512:]) into bf16 MFMA-B-fragment order:
// wef[((kt*32+nt)*64 + lane)*8 + j] = We[kt*32 + (lane>>4)*8 + j][nt*16 + (lane&15)]
__global__ void prep_wef(const float* __restrict__ Wa, ushort_t* __restrict__ wef) {
    int g = blockIdx.x * 256 + threadIdx.x;      // 0..65535
    int kt = g >> 11, nt = (g >> 6) & 31, l = g & 63;
    int kbase = kt * 32 + ((l >> 4) << 3);
    int n = nt * 16 + (l & 15);
    #pragma unroll
    for (int j = 0; j < 8; ++j)
        wef[(size_t)g * 8 + j] = f2bf(Wa[(size_t)(H + kbase + j) * H + n]);
}

// Fused: scores[b][s] = v . tanh( enc[b,s,:] @ We + hb[b,:] )
// WG: 256 thr (4 waves), tile M=64 x N=512 (full), K=1024 in chunks of 64.
// Pipelined: register prefetch of next A chunk + double-buffered LDS;
// barrier is lgkmcnt-only so HBM prefetch stays in flight across it.
__launch_bounds__(256, 2)
__global__ void score_kernel(const float* __restrict__ enc, const ushort_t* __restrict__ wef,
                             const float* __restrict__ hb, const float* __restrict__ v,
                             float* __restrict__ scores) {
    int b = blockIdx.y;
    int s0 = blockIdx.x * 64;
    int tid = threadIdx.x;
    int wave = tid >> 6, lane = tid & 63;
    int q = lane >> 4, nl = lane & 15;

    __shared__ ushort_t As[2][64 * 72];   // double-buffered 64x64 bf16, pad 72
    __shared__ float sred[4][64];

    f32x4 acc[4][8] = {};

    const float* Arow = enc + ((size_t)b * S + s0) * E;
    int srow = tid >> 3;            // 0..31
    int scol = (tid & 7) * 8;       // 0,8,..,56

    const float* src0 = Arow + (size_t)srow * E + scol;
    const float* src1 = Arow + (size_t)(srow + 32) * E + scol;

    // preload kb=0
    float4 x0 = *(const float4*)(src0);
    float4 y0 = *(const float4*)(src0 + 4);
    float4 x1 = *(const float4*)(src1);
    float4 y1 = *(const float4*)(src1 + 4);

    for (int kb = 0; kb < 16; ++kb) {
        ushort_t* Ab = &As[kb & 1][0];
        // convert prefetched regs -> LDS
        uint4 u0, u1;
        u0.x = (unsigned)f2bf(x0.x) | ((unsigned)f2bf(x0.y) << 16);
        u0.y = (unsigned)f2bf(x0.z) | ((unsigned)f2bf(x0.w) << 16);
        u0.z = (unsigned)f2bf(y0.x) | ((unsigned)f2bf(y0.y) << 16);
        u0.w = (unsigned)f2bf(y0.z) | ((unsigned)f2bf(y0.w) << 16);
        u1.x = (unsigned)f2bf(x1.x) | ((unsigned)f2bf(x1.y) << 16);
        u1.y = (unsigned)f2bf(x1.z) | ((unsigned)f2bf(x1.w) << 16);
        u1.z = (unsigned)f2bf(y1.x) | ((unsigned)f2bf(y1.y) << 16);
        u1.w = (unsigned)f2bf(y1.z) | ((unsigned)f2bf(y1.w) << 16);
        *(uint4*)&Ab[srow * 72 + scol]        = u0;
        *(uint4*)&Ab[(srow + 32) * 72 + scol] = u1;

        // issue prefetch for kb+1 (stays in flight across the barrier)
        if (kb < 15) {
            int off = (kb + 1) * 64;
            x0 = *(const float4*)(src0 + off);
            y0 = *(const float4*)(src0 + off + 4);
            x1 = *(const float4*)(src1 + off);
            y1 = *(const float4*)(src1 + off + 4);
        }

        // flush own LDS writes, barrier — do NOT drain vmcnt
        __asm__ __volatile__("s_waitcnt lgkmcnt(0)\n\ts_barrier" ::: "memory");

        #pragma unroll
        for (int ks = 0; ks < 2; ++ks) {
            int kt = kb * 2 + ks;
            bf16x8 afr[4];
            #pragma unroll
            for (int mt = 0; mt < 4; ++mt) {
                int m = mt * 16 + nl;
                afr[mt] = *(const bf16x8*)&Ab[m * 72 + ks * 32 + q * 8];
            }
            #pragma unroll
            for (int ntl = 0; ntl < 8; ++ntl) {
                int nt = wave * 8 + ntl;
                bf16x8 bfr = *(const bf16x8*)&wef[((size_t)(kt * 32 + nt) * 64 + lane) * 8];
                #pragma unroll
                for (int mt = 0; mt < 4; ++mt)
                    acc[mt][ntl] = __builtin_amdgcn_mfma_f32_16x16x32_bf16(
                        afr[mt], bfr, acc[mt][ntl], 0, 0, 0);
            }
        }
        // no second barrier needed: Ab[kb&1] is rewritten only at kb+2,
        // and every wave passes the kb+1 barrier (after its compute) first.
    }

    // Epilogue: C elem (m = mt*16 + q*4 + r, n = wave*128 + ntl*16 + nl)
    float p[16];
    #pragma unroll
    for (int i = 0; i < 16; ++i) p[i] = 0.f;
    #pragma unroll
    for (int ntl = 0; ntl < 8; ++ntl) {
        int n = wave * 128 + ntl * 16 + nl;
        float hv = hb[b * H + n];
        float vv = v[n];
        #pragma unroll
        for (int mt = 0; mt < 4; ++mt)
            #pragma unroll
            for (int r = 0; r < 4; ++r)
                p[mt * 4 + r] += vv * tanhf(acc[mt][ntl][r] + hv);
    }
    #pragma unroll
    for (int off = 1; off < 16; off <<= 1) {
        #pragma unroll
        for (int i = 0; i < 16; ++i) p[i] += __shfl_xor(p[i], off, 64);
    }
    if (nl == 0) {
        #pragma unroll
        for (int mt = 0; mt < 4; ++mt)
            #pragma unroll
            for (int r = 0; r < 4; ++r)
                sred[wave][mt * 16 + q * 4 + r] = p[mt * 4 + r];
    }
    __syncthreads();
    if (tid < 64) {
        float s = sred[0][tid] + sred[1][tid] + sred[2][tid] + sred[3][tid];
        scores[(size_t)b * S + s0 + tid] = s;
    }
}

// softmax over S per b; writes attention weights to out[B*E + ...] and zeros context region
__global__ void softmax_kernel(const float* __restrict__ scores, float* __restrict__ out) {
    int b = blockIdx.x, tid = threadIdx.x;
    const float* row = scores + (size_t)b * S;
    float loc[8];
    float mx = -3.4e38f;
    #pragma unroll
    for (int i = 0; i < 8; ++i) { loc[i] = row[tid + i * 256]; mx = fmaxf(mx, loc[i]); }
    #pragma unroll
    for (int off = 32; off > 0; off >>= 1) mx = fmaxf(mx, __shfl_xor(mx, off, 64));
    __shared__ float wm[4], wsm[4];
    if ((tid & 63) == 0) wm[tid >> 6] = mx;
    __syncthreads();
    mx = fmaxf(fmaxf(wm[0], wm[1]), fmaxf(wm[2], wm[3]));
    float sum = 0.f;
    #pragma unroll
    for (int i = 0; i < 8; ++i) { loc[i] = __expf(loc[i] - mx); sum += loc[i]; }
    #pragma unroll
    for (int off = 32; off > 0; off >>= 1) sum += __shfl_xor(sum, off, 64);
    if ((tid & 63) == 0) wsm[tid >> 6] = sum;
    __syncthreads();
    sum = wsm[0] + wsm[1] + wsm[2] + wsm[3];
    float inv = 1.f / sum;
    #pragma unroll
    for (int i = 0; i < 8; ++i) out[B * E + (size_t)b * S + tid + i * 256] = loc[i] * inv;
    #pragma unroll
    for (int i = 0; i < 4; ++i) out[(size_t)b * E + tid + i * 256] = 0.f;   // zero context for atomics
}

// context[b][e] = sum_s w[b][s] * enc[b][s][e]; float2 per thread, unroll 8
__global__ void context_kernel(const float* __restrict__ enc, const float* __restrict__ w_attn,
                               float* __restrict__ out_ctx) {
    int et = blockIdx.x, sc = blockIdx.y, b = blockIdx.z;
    int e = et * 512 + threadIdx.x * 2;
    const float* w  = w_attn + (size_t)b * S + sc * 128;
    const float* ep = enc + ((size_t)b * S + sc * 128) * E + e;
    float a0 = 0.f, a1 = 0.f;
    #pragma unroll 8
    for (int s = 0; s < 128; ++s) {
        float ws = w[s];
        float2 x = *(const float2*)(ep + (size_t)s * E);
        a0 += ws * x.x;
        a1 += ws * x.y;
    }
    atomicAdd(&out_ctx[(size_t)b * E + e], a0);
    atomicAdd(&out_ctx[(size_t)b * E + e + 1], a1);
}

extern "C" void kernel_launch(void* const* d_in, const int* in_sizes, int n_in,
                              void* d_out, int out_size, void* d_ws, size_t ws_size,
                              hipStream_t stream) {
    const float* hidden = (const float*)d_in[0];
    const float* enc    = (const float*)d_in[1];
    const float* Wa     = (const float*)d_in[2];
    const float* ba     = (const float*)d_in[3];
    const float* v      = (const float*)d_in[4];
    float* out = (float*)d_out;

    char* ws = (char*)d_ws;
    ushort_t* wef = (ushort_t*)ws;                        // 1 MiB  (bf16 We fragments)
    float* hb     = (float*)(ws + (1 << 20));             // 64 KiB
    float* scores = (float*)(ws + (1 << 20) + (1 << 16)); // 256 KiB

    hipMemsetAsync(hb, 0, B * H * sizeof(float), stream);
    prep_hb<<<dim3(B, 8), 256, 0, stream>>>(hidden, Wa, ba, hb);
    prep_wef<<<256, 256, 0, stream>>>(Wa, wef);
    score_kernel<<<dim3(S / 64, B), 256, 0, stream>>>(enc, wef, hb, v, scores);
    softmax_kernel<<<B, 256, 0, stream>>>(scores, out);
    context_kernel<<<dim3(2, 16, B), 256, 0, stream>>>(enc, out + B * E, out);
}